// Round 1
// baseline (82.202 us; speedup 1.0000x reference)
//
#include <hip/hip_runtime.h>

// Problem geometry (all compile-time):
//   input : (64, 64, 12288) f32      -- n, patches, c*ps*ps
//   target: (64, 3, 512, 512) f32    -- n, c, h, w ; ps = 64, n_patches = 8
// out = mean((input - patchify(target))^2), a single f32 scalar.
//
// Element count: 64*64*12288 = 50331648 ; float4 count = 12582912.
// Per-image float4s: 64*3072 = 196608 ; per-patch float4s: 3072 ;
// per-channel-within-patch: 1024 ; per-row-within-patch: 16.
// Target (float4 units): n*196608 + c*65536 + (i*64+py)*128 + j*16 + px4.

#define NBLOCKS   2048
#define NTHREADS  256
#define TOTAL_F4  12582912
#define INV_TOTAL (1.0 / 50331648.0)

__global__ __launch_bounds__(NTHREADS) void mse_partial_kernel(
    const float4* __restrict__ in,
    const float4* __restrict__ tgt,
    float* __restrict__ partial)
{
    const int tid = blockIdx.x * NTHREADS + threadIdx.x;
    float acc = 0.0f;

    #pragma unroll 4
    for (int e = tid; e < TOTAL_F4; e += NBLOCKS * NTHREADS) {
        // decompose input float4 index e -> (n, p, c, py, px4)
        int n   = e / 196608;
        int rem = e - n * 196608;
        int p   = rem / 3072;
        int q   = rem - p * 3072;         // c*1024 + py*16 + px4
        int c   = q / 1024;
        int r   = q - c * 1024;
        int py  = r >> 4;
        int px4 = r & 15;
        int i   = p >> 3;
        int j   = p & 7;

        int t = n * 196608 + c * 65536 + ((i << 6) + py) * 128 + (j << 4) + px4;

        float4 a = in[e];
        float4 b = tgt[t];
        float dx = a.x - b.x;
        float dy = a.y - b.y;
        float dz = a.z - b.z;
        float dw = a.w - b.w;
        acc += dx * dx + dy * dy + dz * dz + dw * dw;
    }

    // wave64 shuffle reduce
    #pragma unroll
    for (int off = 32; off > 0; off >>= 1)
        acc += __shfl_down(acc, off, 64);

    __shared__ float s[NTHREADS / 64];
    const int lane = threadIdx.x & 63;
    const int wave = threadIdx.x >> 6;
    if (lane == 0) s[wave] = acc;
    __syncthreads();
    if (threadIdx.x == 0)
        partial[blockIdx.x] = s[0] + s[1] + s[2] + s[3];
}

__global__ __launch_bounds__(NTHREADS) void mse_final_kernel(
    const float* __restrict__ partial,
    float* __restrict__ out)
{
    double acc = 0.0;
    for (int i = threadIdx.x; i < NBLOCKS; i += NTHREADS)
        acc += (double)partial[i];

    #pragma unroll
    for (int off = 32; off > 0; off >>= 1)
        acc += __shfl_down(acc, off, 64);

    __shared__ double s[NTHREADS / 64];
    const int lane = threadIdx.x & 63;
    const int wave = threadIdx.x >> 6;
    if (lane == 0) s[wave] = acc;
    __syncthreads();
    if (threadIdx.x == 0)
        out[0] = (float)((s[0] + s[1] + s[2] + s[3]) * INV_TOTAL);
}

extern "C" void kernel_launch(void* const* d_in, const int* in_sizes, int n_in,
                              void* d_out, int out_size, void* d_ws, size_t ws_size,
                              hipStream_t stream)
{
    const float4* in  = (const float4*)d_in[0];   // (64, 64, 12288) f32
    const float4* tgt = (const float4*)d_in[1];   // (64, 3, 512, 512) f32
    float* partial    = (float*)d_ws;             // NBLOCKS floats, fully rewritten every call
    float* out        = (float*)d_out;

    mse_partial_kernel<<<NBLOCKS, NTHREADS, 0, stream>>>(in, tgt, partial);
    mse_final_kernel<<<1, NTHREADS, 0, stream>>>(partial, out);
}

// Round 2
// 67.574 us; speedup vs baseline: 1.2165x; 1.2165x over previous
//
#include <hip/hip_runtime.h>

// input : (64, 64, 12288) f32   -- (n, patch p=i*8+j, c*64*64 channel-major per patch)
// target: (64, 3, 512, 512) f32 -- ps = 64, n_patches = 8
// out = mean((input - patchify(target))^2)   (single f32 scalar)
//
// float4 geometry:
//   total f4         = 12582912
//   per image        = 196608 ; per patch = 3072 ; per chan-in-patch = 1024
//   input  f4 idx    = n*196608 + p*3072 + c*1024 + py*16 + px4
//   target f4 idx    = n*196608 + c*65536 + (i*64+py)*128 + j*16 + px4
//
// Block b (of 2048) owns patches 2b, 2b+1  (6144 consecutive input f4).
//   n = b>>5 ; ii = (b&31)>>2 ; jj = ((b&31)&3)*2   (j = jj, jj+1 — same ii, same n)
// Thread tid, iter k (0..11 per patch): e_local = tid + k*256
//   -> c = k>>2, py = (k&3)*16 + (tid>>4), px4 = tid&15
//   input  offset: k*256                (from ip = in + b*6144 + tid)
//   target offset: (k>>2)*65536 + (k&3)*2048   (from per-thread target base)
//   second patch:  input +3072, target +16
// All 48 load addresses are base + compile-time constant -> full unroll, max MLP.

#define NBLOCKS   2048
#define NTHREADS  256
#define INV_TOTAL (1.0 / 50331648.0)

using f32x4 = __attribute__((ext_vector_type(4))) float;

__global__ __launch_bounds__(NTHREADS, 8) void mse_partial_kernel(
    const f32x4* __restrict__ in,
    const f32x4* __restrict__ tgt,
    float* __restrict__ partial)
{
    const int b   = blockIdx.x;
    const int tid = threadIdx.x;

    const int n  = b >> 5;
    const int ii = (b & 31) >> 2;
    const int jj = (b & 3) << 1;

    const f32x4* ip = in + (size_t)b * 6144 + tid;
    const f32x4* tp = tgt + (size_t)n * 196608
                    + (size_t)((ii << 6) + (tid >> 4)) * 128
                    + (jj << 4) + (tid & 15);

    float a0 = 0.f, a1 = 0.f, a2 = 0.f, a3 = 0.f;

    #pragma unroll
    for (int pp = 0; pp < 2; ++pp) {
        #pragma unroll
        for (int k = 0; k < 12; ++k) {
            // input: streamed (non-temporal) so the target array keeps L3 residency
            f32x4 a = __builtin_nontemporal_load(ip + pp * 3072 + k * 256);
            f32x4 t = tp[pp * 16 + (k >> 2) * 65536 + (k & 3) * 2048];
            float dx = a.x - t.x;
            float dy = a.y - t.y;
            float dz = a.z - t.z;
            float dw = a.w - t.w;
            a0 = fmaf(dx, dx, a0);
            a1 = fmaf(dy, dy, a1);
            a2 = fmaf(dz, dz, a2);
            a3 = fmaf(dw, dw, a3);
        }
    }

    float acc = (a0 + a1) + (a2 + a3);

    #pragma unroll
    for (int off = 32; off > 0; off >>= 1)
        acc += __shfl_down(acc, off, 64);

    __shared__ float s[NTHREADS / 64];
    const int lane = threadIdx.x & 63;
    const int wave = threadIdx.x >> 6;
    if (lane == 0) s[wave] = acc;
    __syncthreads();
    if (threadIdx.x == 0)
        partial[blockIdx.x] = s[0] + s[1] + s[2] + s[3];
}

__global__ __launch_bounds__(NTHREADS) void mse_final_kernel(
    const float* __restrict__ partial,
    float* __restrict__ out)
{
    double acc = 0.0;
    for (int i = threadIdx.x; i < NBLOCKS; i += NTHREADS)
        acc += (double)partial[i];

    #pragma unroll
    for (int off = 32; off > 0; off >>= 1)
        acc += __shfl_down(acc, off, 64);

    __shared__ double s[NTHREADS / 64];
    const int lane = threadIdx.x & 63;
    const int wave = threadIdx.x >> 6;
    if (lane == 0) s[wave] = acc;
    __syncthreads();
    if (threadIdx.x == 0)
        out[0] = (float)((s[0] + s[1] + s[2] + s[3]) * INV_TOTAL);
}

extern "C" void kernel_launch(void* const* d_in, const int* in_sizes, int n_in,
                              void* d_out, int out_size, void* d_ws, size_t ws_size,
                              hipStream_t stream)
{
    const f32x4* in  = (const f32x4*)d_in[0];
    const f32x4* tgt = (const f32x4*)d_in[1];
    float* partial   = (float*)d_ws;    // NBLOCKS floats, fully rewritten every call
    float* out       = (float*)d_out;

    mse_partial_kernel<<<NBLOCKS, NTHREADS, 0, stream>>>(in, tgt, partial);
    mse_final_kernel<<<1, NTHREADS, 0, stream>>>(partial, out);
}

// Round 3
// 64.764 us; speedup vs baseline: 1.2693x; 1.0434x over previous
//
#include <hip/hip_runtime.h>

// input : (64, 64, 12288) f32   -- (n, patch p=i*8+j, c*64*64 channel-major per patch)
// target: (64, 3, 512, 512) f32 -- ps = 64, n_patches = 8
// out = mean((input - patchify(target))^2)   (single f32 scalar)
//
// float4 geometry:
//   input  f4 idx = n*196608 + p*3072 + c*1024 + py*16 + px4
//   target f4 idx = n*196608 + c*65536 + (i*64+py)*128 + j*16 + px4
//
// Block b (of 2048) owns patches 2b, 2b+1 (6144 consecutive input f4).
// Thread tid, pair index (pp,k): c = k>>2, py = (k&3)*16 + tid>>4, px4 = tid&15.
// All 48 load addresses are base + compile-time constant.
//
// R3 change: register-batch 12+12 loads per half (launch_bounds(256,4),
// ~110 VGPR) so each wave keeps 24 loads in flight -> ~6 KB/CU outstanding,
// vs ~1.8 KB at VGPR=24 in R2. Tests latency-bound vs fabric-ceiling.

#define NBLOCKS   2048
#define NTHREADS  256
#define INV_TOTAL (1.0 / 50331648.0)

using f32x4 = __attribute__((ext_vector_type(4))) float;

__global__ __launch_bounds__(NTHREADS, 4) void mse_partial_kernel(
    const f32x4* __restrict__ in,
    const f32x4* __restrict__ tgt,
    float* __restrict__ partial)
{
    const int b   = blockIdx.x;
    const int tid = threadIdx.x;

    const int n  = b >> 5;
    const int ii = (b & 31) >> 2;
    const int jj = (b & 3) << 1;

    const f32x4* ip = in + (size_t)b * 6144 + tid;
    const f32x4* tp = tgt + (size_t)n * 196608
                    + (size_t)((ii << 6) + (tid >> 4)) * 128
                    + (jj << 4) + (tid & 15);

    float a0 = 0.f, a1 = 0.f, a2 = 0.f, a3 = 0.f;

    #pragma unroll
    for (int pp = 0; pp < 2; ++pp) {
        f32x4 av[12], tv[12];
        // issue all 24 loads back-to-back: maximize outstanding requests
        #pragma unroll
        for (int k = 0; k < 12; ++k)
            av[k] = __builtin_nontemporal_load(ip + pp * 3072 + k * 256);
        #pragma unroll
        for (int k = 0; k < 12; ++k)
            tv[k] = tp[pp * 16 + (k >> 2) * 65536 + (k & 3) * 2048];
        // consume
        #pragma unroll
        for (int k = 0; k < 12; ++k) {
            float dx = av[k].x - tv[k].x;
            float dy = av[k].y - tv[k].y;
            float dz = av[k].z - tv[k].z;
            float dw = av[k].w - tv[k].w;
            a0 = fmaf(dx, dx, a0);
            a1 = fmaf(dy, dy, a1);
            a2 = fmaf(dz, dz, a2);
            a3 = fmaf(dw, dw, a3);
        }
    }

    float acc = (a0 + a1) + (a2 + a3);

    #pragma unroll
    for (int off = 32; off > 0; off >>= 1)
        acc += __shfl_down(acc, off, 64);

    __shared__ float s[NTHREADS / 64];
    const int lane = threadIdx.x & 63;
    const int wave = threadIdx.x >> 6;
    if (lane == 0) s[wave] = acc;
    __syncthreads();
    if (threadIdx.x == 0)
        partial[blockIdx.x] = s[0] + s[1] + s[2] + s[3];
}

__global__ __launch_bounds__(NTHREADS) void mse_final_kernel(
    const float* __restrict__ partial,
    float* __restrict__ out)
{
    double acc = 0.0;
    for (int i = threadIdx.x; i < NBLOCKS; i += NTHREADS)
        acc += (double)partial[i];

    #pragma unroll
    for (int off = 32; off > 0; off >>= 1)
        acc += __shfl_down(acc, off, 64);

    __shared__ double s[NTHREADS / 64];
    const int lane = threadIdx.x & 63;
    const int wave = threadIdx.x >> 6;
    if (lane == 0) s[wave] = acc;
    __syncthreads();
    if (threadIdx.x == 0)
        out[0] = (float)((s[0] + s[1] + s[2] + s[3]) * INV_TOTAL);
}

extern "C" void kernel_launch(void* const* d_in, const int* in_sizes, int n_in,
                              void* d_out, int out_size, void* d_ws, size_t ws_size,
                              hipStream_t stream)
{
    const f32x4* in  = (const f32x4*)d_in[0];
    const f32x4* tgt = (const f32x4*)d_in[1];
    float* partial   = (float*)d_ws;    // NBLOCKS floats, fully rewritten every call
    float* out       = (float*)d_out;

    mse_partial_kernel<<<NBLOCKS, NTHREADS, 0, stream>>>(in, tgt, partial);
    mse_final_kernel<<<1, NTHREADS, 0, stream>>>(partial, out);
}

// Round 4
// 64.109 us; speedup vs baseline: 1.2822x; 1.0102x over previous
//
#include <hip/hip_runtime.h>

// input : (64, 64, 12288) f32   -- (n, patch p=i*8+j, c*64*64 channel-major per patch)
// target: (64, 3, 512, 512) f32 -- ps = 64, n_patches = 8
// out = mean((input - patchify(target))^2)   (single f32 scalar)
//
// float4 geometry:
//   input  f4 idx = n*196608 + p*3072 + c*1024 + py*16 + px4
//   target f4 idx = n*196608 + c*65536 + (i*64+py)*128 + j*16 + px4
//
// R4: exactly-resident grid. 1024 blocks x 256 thr @ launch_bounds(256,4)
// -> 4 blocks/CU, all blocks resident simultaneously, single uniform round
// (R3's 2048 blocks ran as two sequential occupancy rounds -> double ramp/tail).
// Block b owns 4 consecutive patches (same image, same i, j = jj..jj+3):
//   n = b>>4, ii = (b&15)>>1, jj = ((b&15)&1)*4
//   input f4 base = b*12288 (+ pp*3072 + k*256 + tid)
//   target base   = n*196608 + ((ii<<6)+(tid>>4))*128 + (jj<<4) + (tid&15)
//                   (+ pp*16 + (k>>2)*65536 + (k&3)*2048)
// 96 loads/thread, every address = base + compile-time constant.
// Input loads non-temporal so the target array (201 MB < 256 MB L3) stays
// L3-resident across graph replays; steady-state HBM fetch = input only.

#define NBLOCKS   1024
#define NTHREADS  256
#define INV_TOTAL (1.0 / 50331648.0)

using f32x4 = __attribute__((ext_vector_type(4))) float;

__global__ __launch_bounds__(NTHREADS, 4) void mse_partial_kernel(
    const f32x4* __restrict__ in,
    const f32x4* __restrict__ tgt,
    float* __restrict__ partial)
{
    const int b   = blockIdx.x;
    const int tid = threadIdx.x;

    const int n  = b >> 4;
    const int ii = (b & 15) >> 1;
    const int jj = (b & 1) << 2;

    const f32x4* ip = in + (size_t)b * 12288 + tid;
    const f32x4* tp = tgt + (size_t)n * 196608
                    + (size_t)((ii << 6) + (tid >> 4)) * 128
                    + (jj << 4) + (tid & 15);

    float a0 = 0.f, a1 = 0.f, a2 = 0.f, a3 = 0.f;

    #pragma unroll
    for (int pp = 0; pp < 4; ++pp) {
        f32x4 av[12], tv[12];
        // issue all 24 loads back-to-back: maximize outstanding requests
        #pragma unroll
        for (int k = 0; k < 12; ++k)
            av[k] = __builtin_nontemporal_load(ip + pp * 3072 + k * 256);
        #pragma unroll
        for (int k = 0; k < 12; ++k)
            tv[k] = tp[pp * 16 + (k >> 2) * 65536 + (k & 3) * 2048];
        #pragma unroll
        for (int k = 0; k < 12; ++k) {
            float dx = av[k].x - tv[k].x;
            float dy = av[k].y - tv[k].y;
            float dz = av[k].z - tv[k].z;
            float dw = av[k].w - tv[k].w;
            a0 = fmaf(dx, dx, a0);
            a1 = fmaf(dy, dy, a1);
            a2 = fmaf(dz, dz, a2);
            a3 = fmaf(dw, dw, a3);
        }
    }

    float acc = (a0 + a1) + (a2 + a3);

    #pragma unroll
    for (int off = 32; off > 0; off >>= 1)
        acc += __shfl_down(acc, off, 64);

    __shared__ float s[NTHREADS / 64];
    const int lane = threadIdx.x & 63;
    const int wave = threadIdx.x >> 6;
    if (lane == 0) s[wave] = acc;
    __syncthreads();
    if (threadIdx.x == 0)
        partial[blockIdx.x] = s[0] + s[1] + s[2] + s[3];
}

__global__ __launch_bounds__(NTHREADS) void mse_final_kernel(
    const float* __restrict__ partial,
    float* __restrict__ out)
{
    double acc = 0.0;
    for (int i = threadIdx.x; i < NBLOCKS; i += NTHREADS)
        acc += (double)partial[i];

    #pragma unroll
    for (int off = 32; off > 0; off >>= 1)
        acc += __shfl_down(acc, off, 64);

    __shared__ double s[NTHREADS / 64];
    const int lane = threadIdx.x & 63;
    const int wave = threadIdx.x >> 6;
    if (lane == 0) s[wave] = acc;
    __syncthreads();
    if (threadIdx.x == 0)
        out[0] = (float)((s[0] + s[1] + s[2] + s[3]) * INV_TOTAL);
}

extern "C" void kernel_launch(void* const* d_in, const int* in_sizes, int n_in,
                              void* d_out, int out_size, void* d_ws, size_t ws_size,
                              hipStream_t stream)
{
    const f32x4* in  = (const f32x4*)d_in[0];
    const f32x4* tgt = (const f32x4*)d_in[1];
    float* partial   = (float*)d_ws;    // NBLOCKS floats, fully rewritten every call
    float* out       = (float*)d_out;

    mse_partial_kernel<<<NBLOCKS, NTHREADS, 0, stream>>>(in, tgt, partial);
    mse_final_kernel<<<1, NTHREADS, 0, stream>>>(partial, out);
}